// Round 9
// baseline (65.666 us; speedup 1.0000x reference)
//
#include <hip/hip_runtime.h>
#include <hip/hip_bf16.h>
#include <math.h>

#define B_N 4096
#define D_N 1024
#define K_N 256
#define BK 32                 // k per MFMA step
#define NSTEP (D_N / BK)      // 32

#define AS1 __attribute__((address_space(1)))
#define AS3 __attribute__((address_space(3)))

typedef __attribute__((ext_vector_type(8))) short bf16x8;   // 4 VGPR
typedef __attribute__((ext_vector_type(4))) float f32x4;    // MFMA C/D

static constexpr float K_EPS = 1e-8f;

static __device__ __forceinline__ unsigned short f32_to_bf16_rne(float f) {
    unsigned x = __builtin_bit_cast(unsigned, f);
    unsigned r = (x + 0x7FFFu + ((x >> 16) & 1u)) >> 16;
    return (unsigned short)r;
}
static __device__ __forceinline__ float bf16_bits_to_f32(unsigned short h) {
    unsigned x = ((unsigned)h) << 16;
    return __builtin_bit_cast(float, x);
}

// ---------------------------------------------------------------------------
// Kernel 1: normalize rows; emit bf16 hi/lo split of normalized vectors.
// ---------------------------------------------------------------------------
__global__ __launch_bounds__(256) void knorm_kernel(
    const float* __restrict__ dp, const float* __restrict__ cent,
    ushort* __restrict__ dhi, ushort* __restrict__ dlo,
    ushort* __restrict__ chi, ushort* __restrict__ clo)
{
    int bid = blockIdx.x;
    int tid = threadIdx.x;
    bool isC = bid < K_N;
    int row = isC ? bid : bid - K_N;
    const float* src = isC ? (cent + (size_t)row * D_N) : (dp + (size_t)row * D_N);
    float4 v = reinterpret_cast<const float4*>(src)[tid];
    float s = v.x * v.x + v.y * v.y + v.z * v.z + v.w * v.w;
    #pragma unroll
    for (int o = 32; o > 0; o >>= 1) s += __shfl_down(s, o);
    __shared__ float red[4];
    __shared__ float s_inv;
    if ((tid & 63) == 0) red[tid >> 6] = s;
    __syncthreads();
    if (tid == 0) {
        float t = red[0] + red[1] + red[2] + red[3];
        s_inv = 1.0f / fmaxf(sqrtf(t), K_EPS);
    }
    __syncthreads();
    float inv = s_inv;
    float e[4] = {v.x * inv, v.y * inv, v.z * inv, v.w * inv};
    ushort h4[4], l4[4];
    #pragma unroll
    for (int j = 0; j < 4; ++j) {
        ushort h = f32_to_bf16_rne(e[j]);
        float lo = e[j] - bf16_bits_to_f32(h);
        h4[j] = h;
        l4[j] = f32_to_bf16_rne(lo);
    }
    ushort* ph = (isC ? chi : dhi) + (size_t)row * D_N + tid * 4;
    ushort* pl = (isC ? clo : dlo) + (size_t)row * D_N + tid * 4;
    *reinterpret_cast<ushort4*>(ph) = make_ushort4(h4[0], h4[1], h4[2], h4[3]);
    *reinterpret_cast<ushort4*>(pl) = make_ushort4(l4[0], l4[1], l4[2], l4[3]);
}

// ---------------------------------------------------------------------------
// Kernel 2: sims = dn . cn^T via bf16 split-MFMA (3 products) + fused top-2.
// grid = 256 blocks x 512 threads (8 waves). Block: M=16 rows, N=256.
// A-tile (16 x 1024 hi+lo, 64KB) staged ONCE into LDS, XOR-swizzled
// both-sides (slot c <- global chunk c^(row&7); read with same XOR ->
// 2 lanes/bank-quad = conflict-free). K-loop has NO barriers: B frags are
// per-wave-private, fetched straight from L2-resident chi/clo with 2-deep
// register prefetch (~8 loads in flight; compiler emits counted vmcnt).
// Epilogue: acc -> LDS sims tile, one barrier, butterfly top-2 per wave.
// LDS 80KB -> 2 blocks/CU (4 waves/SIMD).
// ---------------------------------------------------------------------------
__global__ __launch_bounds__(512) void kgemm_kernel(
    const ushort* __restrict__ dhi, const ushort* __restrict__ dlo,
    const ushort* __restrict__ chi, const ushort* __restrict__ clo,
    float* __restrict__ out_sims, float* __restrict__ out_dpidx,
    float* __restrict__ out_hnidx, float* __restrict__ out_top1,
    int* __restrict__ ws_dpidx, int* __restrict__ ws_hnidx)
{
    __shared__ ushort AhL[16 * 1024];   // 32 KB
    __shared__ ushort AlL[16 * 1024];   // 32 KB
    __shared__ float  simsL[16 * 256];  // 16 KB
    int tid  = threadIdx.x;
    int lane = tid & 63;
    int w    = tid >> 6;                               // wave 0..7
    int wu   = __builtin_amdgcn_readfirstlane(w);      // uniform wave id
    int lr   = lane & 15;
    int lg   = lane >> 4;
    int brow = blockIdx.x * 16;

    // ---- stage A hi+lo into LDS, inverse-swizzled source (rule #21) ----
    // chunk = 16B unit; LDS slot (row, c) <- global chunk (row, c^(row&7)).
    {
        #pragma unroll
        for (int half = 0; half < 2; ++half) {
            const char* srcb = (const char*)(half ? dlo : dhi) + (size_t)brow * D_N * 2;
            char* dstb = (char*)(half ? AlL : AhL);
            #pragma unroll
            for (int rnd = 0; rnd < 4; ++rnd) {
                int m  = rnd * 512 + wu * 64;          // wave-uniform chunk base
                int mm = m + lane;                     // this lane's chunk
                int row = mm >> 7, c = mm & 127;
                int cs  = c ^ (row & 7);
                __builtin_amdgcn_global_load_lds(
                    (const AS1 unsigned*)(srcb + row * 2048 + cs * 16),
                    (AS3 unsigned*)(dstb + m * 16), 16, 0, 0);
            }
        }
    }
    __syncthreads();

    f32x4 acc[2] = {};
    const char* AhC = (const char*)AhL;
    const char* AlC = (const char*)AlL;

    auto loadB = [&](int t, bf16x8& h0, bf16x8& l0, bf16x8& h1, bf16x8& l1) {
        int k = t * BK + lg * 8;
        size_t n0 = (size_t)((w * 2 + 0) * 16 + lr) * D_N + k;
        size_t n1 = (size_t)((w * 2 + 1) * 16 + lr) * D_N + k;
        h0 = *reinterpret_cast<const bf16x8*>(&chi[n0]);
        l0 = *reinterpret_cast<const bf16x8*>(&clo[n0]);
        h1 = *reinterpret_cast<const bf16x8*>(&chi[n1]);
        l1 = *reinterpret_cast<const bf16x8*>(&clo[n1]);
    };
    auto step = [&](int t, bf16x8 h0, bf16x8 l0, bf16x8 h1, bf16x8 l1) {
        int g = 4 * t + lg;                      // global 16B chunk in row
        unsigned ca = (unsigned)(g ^ (lr & 7));  // swizzled slot
        unsigned ao = (unsigned)lr * 2048u + ca * 16u;
        bf16x8 ah = *reinterpret_cast<const bf16x8*>(AhC + ao);
        bf16x8 al = *reinterpret_cast<const bf16x8*>(AlC + ao);
        acc[0] = __builtin_amdgcn_mfma_f32_16x16x32_bf16(ah, h0, acc[0], 0, 0, 0);
        acc[0] = __builtin_amdgcn_mfma_f32_16x16x32_bf16(ah, l0, acc[0], 0, 0, 0);
        acc[0] = __builtin_amdgcn_mfma_f32_16x16x32_bf16(al, h0, acc[0], 0, 0, 0);
        acc[1] = __builtin_amdgcn_mfma_f32_16x16x32_bf16(ah, h1, acc[1], 0, 0, 0);
        acc[1] = __builtin_amdgcn_mfma_f32_16x16x32_bf16(ah, l1, acc[1], 0, 0, 0);
        acc[1] = __builtin_amdgcn_mfma_f32_16x16x32_bf16(al, h1, acc[1], 0, 0, 0);
    };

    bf16x8 p0h0, p0l0, p0h1, p0l1, p1h0, p1l0, p1h1, p1l1;
    loadB(0, p0h0, p0l0, p0h1, p0l1);
    loadB(1, p1h0, p1l0, p1h1, p1l1);
    #pragma unroll 1
    for (int t = 0; t < NSTEP; t += 2) {
        step(t, p0h0, p0l0, p0h1, p0l1);
        if (t + 2 < NSTEP) loadB(t + 2, p0h0, p0l0, p0h1, p0l1);
        step(t + 1, p1h0, p1l0, p1h1, p1l1);
        if (t + 3 < NSTEP) loadB(t + 3, p1h0, p1l0, p1h1, p1l1);
    }

    // ---- epilogue: write sims; fused per-row top-2 ----
    // D layout: col = lane&15, row = (lane>>4)*4 + reg (m89-verified)
    #pragma unroll
    for (int tt = 0; tt < 2; ++tt)
        #pragma unroll
        for (int r = 0; r < 4; ++r) {
            int rl = lg * 4 + r;
            int cl = (w * 2 + tt) * 16 + lr;
            out_sims[(size_t)(brow + rl) * K_N + cl] = acc[tt][r];
            simsL[rl * K_N + cl] = acc[tt][r];
        }
    __syncthreads();

    {
        int row_l = w * 2 + (lane >> 5 ? 1 : 1) - 1;   // placeholder avoided below
    }
    // wave w handles rows 2w and 2w+1
    #pragma unroll
    for (int rloc = 0; rloc < 2; ++rloc) {
        int row_l = w * 2 + rloc;
        float4 c = *reinterpret_cast<const float4*>(&simsL[row_l * K_N + lane * 4]);
        float v1b = c.x; int i1 = lane * 4;
        float v2b = -INFINITY; int i2 = 0;
        {
            float vals[3] = {c.y, c.z, c.w};
            #pragma unroll
            for (int j = 0; j < 3; ++j) {
                float val = vals[j]; int idx = lane * 4 + j + 1;
                if (val > v1b) { v2b = v1b; i2 = i1; v1b = val; i1 = idx; }
                else if (val > v2b) { v2b = val; i2 = idx; }
            }
        }
        #pragma unroll
        for (int o = 1; o < 64; o <<= 1) {
            float ov1 = __shfl_xor(v1b, o);
            float ov2 = __shfl_xor(v2b, o);
            int   oi1 = __shfl_xor(i1, o);
            int   oi2 = __shfl_xor(i2, o);
            if (ov1 > v1b || (ov1 == v1b && oi1 < i1)) {
                float nv2; int ni2;
                if (v1b > ov2 || (v1b == ov2 && i1 < oi2)) { nv2 = v1b; ni2 = i1; }
                else { nv2 = ov2; ni2 = oi2; }
                v1b = ov1; i1 = oi1; v2b = nv2; i2 = ni2;
            } else if (ov1 > v2b || (ov1 == v2b && oi1 < i2)) {
                v2b = ov1; i2 = oi1;
            }
        }
        if (lane == 0) {
            int row = brow + row_l;
            out_dpidx[row] = (float)i1;
            out_hnidx[row] = (float)i2;
            out_top1[row]  = v2b;
            ws_dpidx[row]  = i1;
            ws_hnidx[row]  = i2;
        }
    }
}

// ---------------------------------------------------------------------------
// Kernel 3: all remaining outputs. grid = 2*B + K blocks; coalesced stores.
// ---------------------------------------------------------------------------
__global__ __launch_bounds__(256) void kout_kernel(
    const float* __restrict__ cent,
    const int* __restrict__ dpidx, const int* __restrict__ hnidx,
    float* __restrict__ out_dpcent, float* __restrict__ out_hneg,
    float* __restrict__ out_cluster, float* __restrict__ out_indexdp)
{
    int bid = blockIdx.x;
    int tid = threadIdx.x;
    const int4* dpi4 = reinterpret_cast<const int4*>(dpidx);
    if (bid < B_N) {
        int b = bid;
        int i1 = dpidx[b], i2 = hnidx[b];
        float4 v1 = reinterpret_cast<const float4*>(cent + (size_t)i1 * D_N)[tid];
        float4 v2 = reinterpret_cast<const float4*>(cent + (size_t)i2 * D_N)[tid];
        reinterpret_cast<float4*>(out_dpcent + (size_t)b * D_N)[tid] = v1;
        reinterpret_cast<float4*>(out_hneg   + (size_t)b * D_N)[tid] = v2;
    } else if (bid < 2 * B_N) {
        int i = bid - B_N;
        int me = dpidx[i];
        float* dst = out_cluster + (size_t)i * B_N;
        #pragma unroll
        for (int q = 0; q < 4; ++q) {
            int j = q * 1024 + tid * 4;
            int4 ix = dpi4[j >> 2];
            float4 v;
            v.x = (ix.x == me && (j + 0) != i) ? 1.0f : 0.0f;
            v.y = (ix.y == me && (j + 1) != i) ? 1.0f : 0.0f;
            v.z = (ix.z == me && (j + 2) != i) ? 1.0f : 0.0f;
            v.w = (ix.w == me && (j + 3) != i) ? 1.0f : 0.0f;
            *reinterpret_cast<float4*>(dst + j) = v;
        }
    } else {
        int k = bid - 2 * B_N;
        float* dst = out_indexdp + (size_t)k * B_N;
        #pragma unroll
        for (int q = 0; q < 4; ++q) {
            int j = q * 1024 + tid * 4;
            int4 ix = dpi4[j >> 2];
            float4 v;
            v.x = (ix.x == k) ? 1.0f : 0.0f;
            v.y = (ix.y == k) ? 1.0f : 0.0f;
            v.z = (ix.z == k) ? 1.0f : 0.0f;
            v.w = (ix.w == k) ? 1.0f : 0.0f;
            *reinterpret_cast<float4*>(dst + j) = v;
        }
    }
}

extern "C" void kernel_launch(void* const* d_in, const int* in_sizes, int n_in,
                              void* d_out, int out_size, void* d_ws, size_t ws_size,
                              hipStream_t stream)
{
    const float* dp   = (const float*)d_in[0];   // 4096 x 1024 f32
    const float* cent = (const float*)d_in[1];   // 256 x 1024 f32
    // d_in[2] (batch_cos_sim) is unused by the reference outputs.
    float* out = (float*)d_out;

    float* o_sims   = out;                 // 4096*256
    float* o_dpidx  = out + 1048576;       // 4096
    float* o_clust  = out + 1052672;       // 4096*4096
    float* o_idxdp  = out + 17829888;      // 256*4096
    float* o_dpcent = out + 18878464;      // 4096*1024
    float* o_hneg   = out + 23072768;      // 4096*1024
    float* o_hnidx  = out + 27267072;      // 4096
    float* o_top1   = out + 27271168;      // 4096

    char* ws = (char*)d_ws;
    ushort* dhi = (ushort*)ws;                          // 8 MiB
    ushort* dlo = (ushort*)(ws + (8u << 20));           // 8 MiB
    ushort* chi = (ushort*)(ws + (16u << 20));          // 512 KiB
    ushort* clo = (ushort*)(ws + (16u << 20) + (512u << 10));   // 512 KiB
    int*    widx = (int*)(ws + (17u << 20));            // 16 KiB
    int*    whn  = (int*)(ws + (17u << 20) + 16384);    // 16 KiB

    hipLaunchKernelGGL(knorm_kernel, dim3(K_N + B_N), dim3(256), 0, stream,
                       dp, cent, dhi, dlo, chi, clo);
    hipLaunchKernelGGL(kgemm_kernel, dim3(B_N / 16), dim3(512), 0, stream,
                       dhi, dlo, chi, clo,
                       o_sims, o_dpidx, o_hnidx, o_top1, widx, whn);
    hipLaunchKernelGGL(kout_kernel, dim3(2 * B_N + K_N), dim3(256), 0, stream,
                       cent, widx, whn, o_dpcent, o_hneg, o_clust, o_idxdp);
}

// Round 10
// 60.990 us; speedup vs baseline: 1.0767x; 1.0767x over previous
//
#include <hip/hip_runtime.h>
#include <hip/hip_bf16.h>
#include <math.h>

#define B_N 4096
#define D_N 1024
#define K_N 256
#define BK 32                 // k per MFMA step
#define NSTEP (D_N / BK)      // 32

typedef __attribute__((ext_vector_type(8))) short bf16x8;           // 4 VGPR
typedef __attribute__((ext_vector_type(8))) unsigned short u16x8;   // 4 VGPR
typedef __attribute__((ext_vector_type(4))) float f32x4;            // MFMA C/D

static constexpr float K_EPS = 1e-8f;

static __device__ __forceinline__ unsigned short f32_to_bf16_rne(float f) {
    unsigned x = __builtin_bit_cast(unsigned, f);
    unsigned r = (x + 0x7FFFu + ((x >> 16) & 1u)) >> 16;
    return (unsigned short)r;
}
static __device__ __forceinline__ float bf16_bits_to_f32(unsigned short h) {
    unsigned x = ((unsigned)h) << 16;
    return __builtin_bit_cast(float, x);
}

// ---------------------------------------------------------------------------
// Kernel 1: centroid normalize + bf16 hi/lo split. grid = 256 x 256.
// ---------------------------------------------------------------------------
__global__ __launch_bounds__(256) void kcent_kernel(
    const float* __restrict__ cent,
    ushort* __restrict__ chi, ushort* __restrict__ clo)
{
    int row = blockIdx.x;
    int tid = threadIdx.x;
    float4 v = reinterpret_cast<const float4*>(cent + (size_t)row * D_N)[tid];
    float s = v.x * v.x + v.y * v.y + v.z * v.z + v.w * v.w;
    #pragma unroll
    for (int o = 32; o > 0; o >>= 1) s += __shfl_down(s, o);
    __shared__ float red[4];
    __shared__ float s_inv;
    if ((tid & 63) == 0) red[tid >> 6] = s;
    __syncthreads();
    if (tid == 0) {
        float t = red[0] + red[1] + red[2] + red[3];
        s_inv = 1.0f / fmaxf(sqrtf(t), K_EPS);
    }
    __syncthreads();
    float inv = s_inv;
    float e[4] = {v.x * inv, v.y * inv, v.z * inv, v.w * inv};
    ushort h4[4], l4[4];
    #pragma unroll
    for (int j = 0; j < 4; ++j) {
        ushort h = f32_to_bf16_rne(e[j]);
        float lo = e[j] - bf16_bits_to_f32(h);
        h4[j] = h;
        l4[j] = f32_to_bf16_rne(lo);
    }
    *reinterpret_cast<ushort4*>(chi + (size_t)row * D_N + tid * 4) =
        make_ushort4(h4[0], h4[1], h4[2], h4[3]);
    *reinterpret_cast<ushort4*>(clo + (size_t)row * D_N + tid * 4) =
        make_ushort4(l4[0], l4[1], l4[2], l4[3]);
}

// ---------------------------------------------------------------------------
// Kernel 2 (main): fused dp-normalize + split-MFMA GEMM + top-2 + gathers.
// grid = 256 blocks x 512 threads (8 waves). Block: M=16 dp rows, N=256.
//  Stage 1: load 16 rows f32 (the one unavoidable dp read), 32 thr/row,
//           shfl_xor row-reduce, scale, split to bf16 hi/lo, ds_write into
//           XOR-swizzled A-tiles (slot = chunk ^ (row&7); linear per wave).
//  Stage 2: barrier-free K-loop (R9-verified): per-wave-private B frags from
//           L2-resident chi/clo, 2-deep register prefetch, 6 MFMA/step.
//  Stage 3: sims write + LDS sims tile; per-wave top-2 butterfly (rows 2w,
//           2w+1); lane-shared i1/i2 -> gather cent[i1],cent[i2] -> write
//           dp_centroid / hard_negative rows; lane 0 writes indices.
// LDS 80 KB -> 2 blocks/CU.
// ---------------------------------------------------------------------------
__global__ __launch_bounds__(512, 4) void kmain_kernel(
    const float* __restrict__ dp, const float* __restrict__ cent,
    const ushort* __restrict__ chi, const ushort* __restrict__ clo,
    float* __restrict__ out_sims, float* __restrict__ out_dpidx,
    float* __restrict__ out_hnidx, float* __restrict__ out_top1,
    float* __restrict__ out_dpcent, float* __restrict__ out_hneg,
    int* __restrict__ ws_dpidx)
{
    __shared__ ushort AhL[16 * 1024];   // 32 KB (swizzled)
    __shared__ ushort AlL[16 * 1024];   // 32 KB
    __shared__ float  simsL[16 * 256];  // 16 KB
    int tid  = threadIdx.x;
    int lane = tid & 63;
    int w    = tid >> 6;        // wave 0..7
    int lr   = lane & 15;
    int lg   = lane >> 4;
    int brow = blockIdx.x * 16;

    // ---- B prefetch machinery (R9-verified) ----
    auto loadB = [&](int t, bf16x8& h0, bf16x8& l0, bf16x8& h1, bf16x8& l1) {
        int k = t * BK + lg * 8;
        size_t n0 = (size_t)((w * 2 + 0) * 16 + lr) * D_N + k;
        size_t n1 = (size_t)((w * 2 + 1) * 16 + lr) * D_N + k;
        h0 = *reinterpret_cast<const bf16x8*>(&chi[n0]);
        l0 = *reinterpret_cast<const bf16x8*>(&clo[n0]);
        h1 = *reinterpret_cast<const bf16x8*>(&chi[n1]);
        l1 = *reinterpret_cast<const bf16x8*>(&clo[n1]);
    };
    bf16x8 p0h0, p0l0, p0h1, p0l1, p1h0, p1l0, p1h1, p1l1;
    loadB(0, p0h0, p0l0, p0h1, p0l1);   // in flight during A-stage
    loadB(1, p1h0, p1l0, p1h1, p1l1);

    // ---- Stage 1: fused dp normalization into swizzled A-tiles ----
    {
        int grp = tid & 31;          // 32 threads per row
        int row = tid >> 5;          // 0..15
        const float* rsrc = dp + (size_t)(brow + row) * D_N;
        float4 va[8];
        float s = 0.f;
        #pragma unroll
        for (int q = 0; q < 4; ++q) {
            va[2 * q]     = *reinterpret_cast<const float4*>(rsrc + grp * 8 + q * 256);
            va[2 * q + 1] = *reinterpret_cast<const float4*>(rsrc + grp * 8 + q * 256 + 4);
            s += va[2*q].x*va[2*q].x + va[2*q].y*va[2*q].y
               + va[2*q].z*va[2*q].z + va[2*q].w*va[2*q].w;
            s += va[2*q+1].x*va[2*q+1].x + va[2*q+1].y*va[2*q+1].y
               + va[2*q+1].z*va[2*q+1].z + va[2*q+1].w*va[2*q+1].w;
        }
        #pragma unroll
        for (int o = 1; o < 32; o <<= 1) s += __shfl_xor(s, o);
        float inv = 1.0f / fmaxf(sqrtf(s), K_EPS);
        #pragma unroll
        for (int q = 0; q < 4; ++q) {
            int g    = q * 32 + grp;
            int slot = g ^ (row & 7);
            float e0 = va[2*q].x*inv,   e1 = va[2*q].y*inv;
            float e2 = va[2*q].z*inv,   e3 = va[2*q].w*inv;
            float e4 = va[2*q+1].x*inv, e5 = va[2*q+1].y*inv;
            float e6 = va[2*q+1].z*inv, e7 = va[2*q+1].w*inv;
            ushort h0=f32_to_bf16_rne(e0), h1=f32_to_bf16_rne(e1),
                   h2=f32_to_bf16_rne(e2), h3=f32_to_bf16_rne(e3),
                   h4=f32_to_bf16_rne(e4), h5=f32_to_bf16_rne(e5),
                   h6=f32_to_bf16_rne(e6), h7=f32_to_bf16_rne(e7);
            u16x8 hv = {h0,h1,h2,h3,h4,h5,h6,h7};
            u16x8 lv = {f32_to_bf16_rne(e0 - bf16_bits_to_f32(h0)),
                        f32_to_bf16_rne(e1 - bf16_bits_to_f32(h1)),
                        f32_to_bf16_rne(e2 - bf16_bits_to_f32(h2)),
                        f32_to_bf16_rne(e3 - bf16_bits_to_f32(h3)),
                        f32_to_bf16_rne(e4 - bf16_bits_to_f32(h4)),
                        f32_to_bf16_rne(e5 - bf16_bits_to_f32(h5)),
                        f32_to_bf16_rne(e6 - bf16_bits_to_f32(h6)),
                        f32_to_bf16_rne(e7 - bf16_bits_to_f32(h7))};
            *reinterpret_cast<u16x8*>(&AhL[row * 1024 + slot * 8]) = hv;
            *reinterpret_cast<u16x8*>(&AlL[row * 1024 + slot * 8]) = lv;
        }
    }
    __syncthreads();

    // ---- Stage 2: barrier-free K-loop ----
    f32x4 acc[2] = {};
    const char* AhC = (const char*)AhL;
    const char* AlC = (const char*)AlL;
    auto step = [&](int t, bf16x8 h0, bf16x8 l0, bf16x8 h1, bf16x8 l1) {
        int g = 4 * t + lg;                      // global 16B chunk in row
        unsigned ca = (unsigned)(g ^ (lr & 7));  // swizzled slot
        unsigned ao = (unsigned)lr * 2048u + ca * 16u;
        bf16x8 ah = *reinterpret_cast<const bf16x8*>(AhC + ao);
        bf16x8 al = *reinterpret_cast<const bf16x8*>(AlC + ao);
        acc[0] = __builtin_amdgcn_mfma_f32_16x16x32_bf16(ah, h0, acc[0], 0, 0, 0);
        acc[0] = __builtin_amdgcn_mfma_f32_16x16x32_bf16(ah, l0, acc[0], 0, 0, 0);
        acc[0] = __builtin_amdgcn_mfma_f32_16x16x32_bf16(al, h0, acc[0], 0, 0, 0);
        acc[1] = __builtin_amdgcn_mfma_f32_16x16x32_bf16(ah, h1, acc[1], 0, 0, 0);
        acc[1] = __builtin_amdgcn_mfma_f32_16x16x32_bf16(ah, l1, acc[1], 0, 0, 0);
        acc[1] = __builtin_amdgcn_mfma_f32_16x16x32_bf16(al, h1, acc[1], 0, 0, 0);
    };
    #pragma unroll 1
    for (int t = 0; t < NSTEP; t += 2) {
        step(t, p0h0, p0l0, p0h1, p0l1);
        if (t + 2 < NSTEP) loadB(t + 2, p0h0, p0l0, p0h1, p0l1);
        step(t + 1, p1h0, p1l0, p1h1, p1l1);
        if (t + 3 < NSTEP) loadB(t + 3, p1h0, p1l0, p1h1, p1l1);
    }

    // ---- Stage 3: sims + fused top-2 + gathers ----
    // D layout: col = lane&15, row = (lane>>4)*4 + reg (m89-verified)
    #pragma unroll
    for (int tt = 0; tt < 2; ++tt)
        #pragma unroll
        for (int r = 0; r < 4; ++r) {
            int rl = lg * 4 + r;
            int cl = (w * 2 + tt) * 16 + lr;
            out_sims[(size_t)(brow + rl) * K_N + cl] = acc[tt][r];
            simsL[rl * K_N + cl] = acc[tt][r];
        }
    __syncthreads();

    const float4* cent4 = reinterpret_cast<const float4*>(cent);
    #pragma unroll
    for (int rloc = 0; rloc < 2; ++rloc) {
        int row_l = w * 2 + rloc;
        float4 c = *reinterpret_cast<const float4*>(&simsL[row_l * K_N + lane * 4]);
        float v1b = c.x; int i1 = lane * 4;
        float v2b = -INFINITY; int i2 = 0;
        {
            float vals[3] = {c.y, c.z, c.w};
            #pragma unroll
            for (int j = 0; j < 3; ++j) {
                float val = vals[j]; int idx = lane * 4 + j + 1;
                if (val > v1b) { v2b = v1b; i2 = i1; v1b = val; i1 = idx; }
                else if (val > v2b) { v2b = val; i2 = idx; }
            }
        }
        #pragma unroll
        for (int o = 1; o < 64; o <<= 1) {
            float ov1 = __shfl_xor(v1b, o);
            float ov2 = __shfl_xor(v2b, o);
            int   oi1 = __shfl_xor(i1, o);
            int   oi2 = __shfl_xor(i2, o);
            if (ov1 > v1b || (ov1 == v1b && oi1 < i1)) {
                float nv2; int ni2;
                if (v1b > ov2 || (v1b == ov2 && i1 < oi2)) { nv2 = v1b; ni2 = i1; }
                else { nv2 = ov2; ni2 = oi2; }
                v1b = ov1; i1 = oi1; v2b = nv2; i2 = ni2;
            } else if (ov1 > v2b || (ov1 == v2b && oi1 < i2)) {
                v2b = ov1; i2 = oi1;
            }
        }
        int row = brow + row_l;
        // all lanes hold i1/i2: gather + write this row's outputs
        #pragma unroll
        for (int q = 0; q < 4; ++q) {
            float4 g1 = cent4[(size_t)i1 * 256 + q * 64 + lane];
            float4 g2 = cent4[(size_t)i2 * 256 + q * 64 + lane];
            reinterpret_cast<float4*>(out_dpcent + (size_t)row * D_N)[q * 64 + lane] = g1;
            reinterpret_cast<float4*>(out_hneg   + (size_t)row * D_N)[q * 64 + lane] = g2;
        }
        if (lane == 0) {
            out_dpidx[row] = (float)i1;
            out_hnidx[row] = (float)i2;
            out_top1[row]  = v2b;
            ws_dpidx[row]  = i1;
        }
    }
}

// ---------------------------------------------------------------------------
// Kernel 3: dp_cluster (B x B) + index_dp (K x B). grid = B_N + K_N blocks;
// fully coalesced float4 stores (1 KB/wave-instr).
// ---------------------------------------------------------------------------
__global__ __launch_bounds__(256) void kclust_kernel(
    const int* __restrict__ dpidx,
    float* __restrict__ out_cluster, float* __restrict__ out_indexdp)
{
    int bid = blockIdx.x;
    int tid = threadIdx.x;
    const int4* dpi4 = reinterpret_cast<const int4*>(dpidx);
    if (bid < B_N) {
        int i = bid;
        int me = dpidx[i];
        float* dst = out_cluster + (size_t)i * B_N;
        #pragma unroll
        for (int q = 0; q < 4; ++q) {
            int j = q * 1024 + tid * 4;
            int4 ix = dpi4[j >> 2];
            float4 v;
            v.x = (ix.x == me && (j + 0) != i) ? 1.0f : 0.0f;
            v.y = (ix.y == me && (j + 1) != i) ? 1.0f : 0.0f;
            v.z = (ix.z == me && (j + 2) != i) ? 1.0f : 0.0f;
            v.w = (ix.w == me && (j + 3) != i) ? 1.0f : 0.0f;
            *reinterpret_cast<float4*>(dst + j) = v;
        }
    } else {
        int k = bid - B_N;
        float* dst = out_indexdp + (size_t)k * B_N;
        #pragma unroll
        for (int q = 0; q < 4; ++q) {
            int j = q * 1024 + tid * 4;
            int4 ix = dpi4[j >> 2];
            float4 v;
            v.x = (ix.x == k) ? 1.0f : 0.0f;
            v.y = (ix.y == k) ? 1.0f : 0.0f;
            v.z = (ix.z == k) ? 1.0f : 0.0f;
            v.w = (ix.w == k) ? 1.0f : 0.0f;
            *reinterpret_cast<float4*>(dst + j) = v;
        }
    }
}

extern "C" void kernel_launch(void* const* d_in, const int* in_sizes, int n_in,
                              void* d_out, int out_size, void* d_ws, size_t ws_size,
                              hipStream_t stream)
{
    const float* dp   = (const float*)d_in[0];   // 4096 x 1024 f32
    const float* cent = (const float*)d_in[1];   // 256 x 1024 f32
    // d_in[2] (batch_cos_sim) is unused by the reference outputs.
    float* out = (float*)d_out;

    float* o_sims   = out;                 // 4096*256
    float* o_dpidx  = out + 1048576;       // 4096
    float* o_clust  = out + 1052672;       // 4096*4096
    float* o_idxdp  = out + 17829888;      // 256*4096
    float* o_dpcent = out + 18878464;      // 4096*1024
    float* o_hneg   = out + 23072768;      // 4096*1024
    float* o_hnidx  = out + 27267072;      // 4096
    float* o_top1   = out + 27271168;      // 4096

    char* ws = (char*)d_ws;
    ushort* chi  = (ushort*)ws;                         // 512 KiB
    ushort* clo  = (ushort*)(ws + (512u << 10));        // 512 KiB
    int*    widx = (int*)(ws + (1u << 20));             // 16 KiB

    hipLaunchKernelGGL(kcent_kernel, dim3(K_N), dim3(256), 0, stream,
                       cent, chi, clo);
    hipLaunchKernelGGL(kmain_kernel, dim3(B_N / 16), dim3(512), 0, stream,
                       dp, cent, chi, clo,
                       o_sims, o_dpidx, o_hnidx, o_top1,
                       o_dpcent, o_hneg, widx);
    hipLaunchKernelGGL(kclust_kernel, dim3(B_N + K_N), dim3(256), 0, stream,
                       widx, o_clust, o_idxdp);
}